// Round 16
// baseline (188.684 us; speedup 1.0000x reference)
//
#include <hip/hip_runtime.h>
#include <stdint.h>

// Layered Bayesian net marginal chain: 63 sequential layers, M=16384 nodes,
// K=4 parents, C=16 CPT entries per node.
//
// Structure (R5->R12, best=93us, PASSED): global fine-grained dataflow.
// Marginals are strictly positive, so the DATA is its own ready-flag:
// sentinel-init rows, relaxed AGENT-scope write-through stores, consumers
// poll their own 4 parent slots (inline-asm sc0 sc1 loads, hand-placed
// vmcnt(4), staggered A/B batches, per-lane early publish). Statics are
// compiler-owned loads prefetched 2 links deep (hardware-retired by the
// spin's vmcnt(4), so compiler waits are cheap). No barriers, no fences.
//
// R12 post-mortem: 1.43us/link remains ~2x the node-level link latency.
// Dominant term: CONSUMER-side wave coupling — a wave can't START polling
// link t+1 until __all lanes finish link t (max over ~250 producers, every
// link). R13 = SKEW-1 TOLERANCE: per-lane 2-stage state machine. A lane
// whose parents arrive publishes AND immediately re-points its polls at its
// next link's parents (statics for t+1 already in regs, idx prefetched).
// The wave window shifts one link BEHIND the leading lanes, so the wave-max
// lags a full link and rarely binds; pace becomes max-over-4-parents.
//  - stale-batch hazard (in-flight polls to pre-advance addresses): 1-check
//    ignore flag; exactly one stale batch possible per advance/shift.
//  - poll outputs live continuously in ONE loop (no cross-body register
//    death -> avoids R11's in-flight-write-to-recycled-reg failure).
//  - monotonic slots: any >=0 ever observed is the true final value.
//  - escalation valve (vmcnt(0) + compiler-load loop) keeps it hang-proof.

namespace {
constexpr int kLayers  = 63;      // links (row t -> row t+1), rows 0..63
constexpr int kM       = 16384;   // nodes per layer
constexpr int kBlocks  = 256;     // 1 block (1 wave) per CU
constexpr int kThreads = 64;      // kBlocks*kThreads == kM, 1 thread per node
constexpr float kSentinel = -1.0f;
}

// Re-init the whole out buffer (rows 0..63) to sentinel each launch.
// Normal cached stores; kernel-end writeback makes them visible to the
// chain kernel's agent-scope (cache-bypassing) polls.
__global__ void init_sentinel_kernel(float4* __restrict__ out4) {
  int i = blockIdx.x * blockDim.x + threadIdx.x;   // 262144 float4 total
  out4[i] = make_float4(kSentinel, kSentinel, kSentinel, kSentinel);
}

__device__ __forceinline__ float fsig(float x) {
  // sigmoid; fp32 fast-math is far inside the 1.8e-2 abs threshold
  return __fdividef(1.0f, 1.0f + __expf(-x));
}

// Agent-scope (device-coherent) accesses: bypass the non-coherent per-XCD
// L1/L2, hit the coherence point directly. No cache-wide maintenance.
__device__ __forceinline__ void agent_store(float* p, float v) {
  __hip_atomic_store(p, v, __ATOMIC_RELAXED, __HIP_MEMORY_SCOPE_AGENT);
}
__device__ __forceinline__ float agent_load(const float* p) {
  return __hip_atomic_load(p, __ATOMIC_RELAXED, __HIP_MEMORY_SCOPE_AGENT);
}

// Issue 4 agent read-through polls as raw asm: WE own the waitcnt (the
// compiler cannot see these), giving exact control of check cadence.
#define POLL_ISSUE4(r0, r1, r2, r3, A0, A1, A2, A3)                         \
  asm volatile("global_load_dword %0, %4, off sc0 sc1\n\t"                  \
               "global_load_dword %1, %5, off sc0 sc1\n\t"                  \
               "global_load_dword %2, %6, off sc0 sc1\n\t"                  \
               "global_load_dword %3, %7, off sc0 sc1"                      \
               : "=&v"(r0), "=&v"(r1), "=&v"(r2), "=&v"(r3)                 \
               : "v"(A0), "v"(A1), "v"(A2), "v"(A3)                         \
               : "memory")

// weight[c] factorizes over parents (MSB-first bit order, matches _configs):
// c = b0 b1 b2 b3, fk(1)=pk, fk(0)=1-pk.
__device__ __forceinline__ float combine16(const float* s,
                                           float p0, float p1, float p2, float p3) {
  float q0 = 1.0f - p0, q1 = 1.0f - p1, q2 = 1.0f - p2, q3 = 1.0f - p3;
  float w0 = q2 * q3, w1 = q2 * p3, w2 = p2 * q3, w3 = p2 * p3;   // (b2,b3)
  float i0 = s[0]  * w0 + s[1]  * w1 + s[2]  * w2 + s[3]  * w3;   // (b0,b1)=(0,0)
  float i1 = s[4]  * w0 + s[5]  * w1 + s[6]  * w2 + s[7]  * w3;   // (0,1)
  float i2 = s[8]  * w0 + s[9]  * w1 + s[10] * w2 + s[11] * w3;   // (1,0)
  float i3 = s[12] * w0 + s[13] * w1 + s[14] * w2 + s[15] * w3;   // (1,1)
  return (q0 * q1) * i0 + (q0 * p1) * i1 + (p0 * q1) * i2 + (p0 * p1) * i3;
}

#define SIG16(S, V0, V1, V2, V3)                                              \
  S[0]  = fsig((V0).x); S[1]  = fsig((V0).y); S[2]  = fsig((V0).z); S[3]  = fsig((V0).w); \
  S[4]  = fsig((V1).x); S[5]  = fsig((V1).y); S[6]  = fsig((V1).z); S[7]  = fsig((V1).w); \
  S[8]  = fsig((V2).x); S[9]  = fsig((V2).y); S[10] = fsig((V2).z); S[11] = fsig((V2).w); \
  S[12] = fsig((V3).x); S[13] = fsig((V3).y); S[14] = fsig((V3).z); S[15] = fsig((V3).w)

// Per-lane fire: if this lane's current 4 parents arrived (and the batch is
// not stale), publish and advance its state machine by one stage.
// stage0 (done0=false): gather link t parents (values P*), publish row t+1
//   with s_cur, then re-point polls at link t+1 parents (rowt1 + idx1).
// stage1 (done0, !done1): gather link t+1 parents, publish row t+2 with
//   s_next, then idle until the wave's window shifts.
#define FIRE(P0, P1, P2, P3)                                                 \
  {                                                                          \
    bool need_ = !(done0 & done1);                                           \
    bool rdy_ = (P0 >= 0.f) & (P1 >= 0.f) & (P2 >= 0.f) & (P3 >= 0.f);       \
    if (need_ & rdy_ & !stale) {                                             \
      float sv[16];                                                          \
      _Pragma("unroll")                                                      \
      for (int i_ = 0; i_ < 16; ++i_) sv[i_] = done0 ? sn[i_] : sc[i_];      \
      float* d_ = done0 ? (pub0 + kM) : pub0;                                \
      agent_store(d_, combine16(sv, P0, P1, P2, P3));                        \
      if (!done0) {                                                          \
        done0 = true;                                                        \
        if (has1) {                                                          \
          A0 = rowt1 + idx1.x; A1 = rowt1 + idx1.y;                          \
          A2 = rowt1 + idx1.z; A3 = rowt1 + idx1.w;                          \
          stale = true;   /* one in-flight batch has old addresses */        \
        } else {                                                             \
          done1 = true;   /* no stage1 in the last window */                 \
        }                                                                    \
      } else {                                                               \
        done1 = true;                                                        \
      }                                                                      \
    } else if (stale) {                                                      \
      stale = false;      /* ignored exactly one stale-batch check */        \
    }                                                                        \
  }

// Wave-uniform window shift (guarded by __all(done0)): advance base link,
// rotate statics (s_cur <- s_next; s_next from the 2-deep prefetch), issue
// the next prefetch, remap roles. Lanes that already finished stage1 start
// polling the NEW stage1 (their in-flight batch becomes stale). Compiler
// owns the statics waits; its vmcnt(0) here only drains ~RTT/2-old polls.
#define SHIFT()                                                              \
  {                                                                          \
    t += 1;                                                                  \
    if (t == kLayers) goto all_done;                                         \
    rowt1 += kM; pub0 += kM;                                                 \
    _Pragma("unroll")                                                        \
    for (int i_ = 0; i_ < 16; ++i_) sc[i_] = sn[i_];                         \
    SIG16(sn, f0, f1, f2, f3);                                               \
    idx1 = idxf;                                                             \
    {                                                                        \
      const int tpp_ = (t + 2 < kLayers) ? (t + 2) : (kLayers - 1);          \
      const size_t bn_ = (size_t)tpp_ * kM + m;                              \
      idxf = pidx[bn_];                                                      \
      f0 = lg[bn_ * 4 + 0]; f1 = lg[bn_ * 4 + 1];                            \
      f2 = lg[bn_ * 4 + 2]; f3 = lg[bn_ * 4 + 3];                            \
    }                                                                        \
    has1 = (t + 1 < kLayers);                                                \
    {                                                                        \
      bool nd0_ = done1;                                                     \
      done0 = nd0_;                                                          \
      done1 = !has1;                                                         \
      if (nd0_ & has1) {          /* enter NEW stage1 polling now */         \
        A0 = rowt1 + idx1.x; A1 = rowt1 + idx1.y;                            \
        A2 = rowt1 + idx1.z; A3 = rowt1 + idx1.w;                            \
        stale = true;                                                        \
      }                                                                      \
    }                                                                        \
    tries = 0;                                                               \
  }

__global__ __launch_bounds__(kThreads, 1) void bayes_chain_kernel(
    const float* __restrict__ root_logits,   // [kM]
    const float* __restrict__ layer_logits,  // [kLayers][kM][16]
    const int*   __restrict__ parent_idx,    // [kLayers][kM][4]
    float* __restrict__ out)                 // [kLayers+1][kM]
{
  const int m = blockIdx.x * kThreads + threadIdx.x;

  const int4*   pidx = reinterpret_cast<const int4*>(parent_idx);     // [63][M]
  const float4* lg   = reinterpret_cast<const float4*>(layer_logits); // [63][M][4]

  // ---- row 0: root marginals, write-through so consumers' polls see them ----
  agent_store(&out[m], fsig(root_logits[m]));

  // link 0 + link 1 statics (compiler loads; no asm polls outstanding yet)
  int4 idx0 = pidx[m];
  float4 c0 = lg[(size_t)m * 4 + 0], c1 = lg[(size_t)m * 4 + 1];
  float4 c2 = lg[(size_t)m * 4 + 2], c3 = lg[(size_t)m * 4 + 3];
  float sc[16]; SIG16(sc, c0, c1, c2, c3);          // s_cur  (link t)
  const size_t b1 = (size_t)kM + m;
  int4 idx1 = pidx[b1];                              // idx (link t+1)
  float4 d0 = lg[b1 * 4 + 0], d1 = lg[b1 * 4 + 1];
  float4 d2 = lg[b1 * 4 + 2], d3 = lg[b1 * 4 + 3];
  float sn[16]; SIG16(sn, d0, d1, d2, d3);          // s_next (link t+1)
  // 2-deep prefetch: raw statics for link t+2 (consumed at SHIFT)
  int4 idxf; float4 f0, f1, f2, f3;
  {
    const size_t b2 = (size_t)2 * kM + m;
    idxf = pidx[b2];
    f0 = lg[b2 * 4 + 0]; f1 = lg[b2 * 4 + 1];
    f2 = lg[b2 * 4 + 2]; f3 = lg[b2 * 4 + 3];
  }

  const float* rowt1 = out + kM;     // stage1 gather base = row t+1
  float*       pub0  = out + kM + m; // stage0 publish slot = row t+1
  const float* A0 = out + idx0.x;    // stage0 gather: row t (= row 0)
  const float* A1 = out + idx0.y;
  const float* A2 = out + idx0.z;
  const float* A3 = out + idx0.w;

  bool done0 = false, done1 = false, stale = false;
  bool has1 = true;                  // t=0: link 1 exists
  int t = 0;
  int tries = 0;

  float pA0, pA1, pA2, pA3, pB0, pB1, pB2, pB3;
  POLL_ISSUE4(pA0, pA1, pA2, pA3, A0, A1, A2, A3);
  __builtin_amdgcn_s_sleep(8);       // ~213ns: offset batches ~RTT/2
  POLL_ISSUE4(pB0, pB1, pB2, pB3, A0, A1, A2, A3);

  for (;;) {
    // ---- check batch A (vmcnt(4): retires A + everything older) ----
    asm volatile("s_waitcnt vmcnt(4)" ::: "memory");
    __builtin_amdgcn_sched_barrier(0);
    FIRE(pA0, pA1, pA2, pA3);
    if (__all(done0)) SHIFT();
    POLL_ISSUE4(pA0, pA1, pA2, pA3, A0, A1, A2, A3);

    // ---- check batch B ----
    asm volatile("s_waitcnt vmcnt(4)" ::: "memory");
    __builtin_amdgcn_sched_barrier(0);
    FIRE(pB0, pB1, pB2, pB3);
    if (__all(done0)) SHIFT();

    if (++tries > 4096) {
      // escalation valve: drain manual queue, compiler-load state machine
      tries = 0;
      asm volatile("s_waitcnt vmcnt(0)" ::: "memory");
      __builtin_amdgcn_sched_barrier(0);
      stale = false;
      while (!__all(done0)) {
        float x0 = agent_load(A0), x1 = agent_load(A1);
        float x2 = agent_load(A2), x3 = agent_load(A3);
        FIRE(x0, x1, x2, x3);
      }
      stale = false;                 // both batches reissued fresh below
      POLL_ISSUE4(pA0, pA1, pA2, pA3, A0, A1, A2, A3);
      __builtin_amdgcn_s_sleep(8);
      // next __all(done0) check (top of loop after B-reissue) shifts
    }
    POLL_ISSUE4(pB0, pB1, pB2, pB3, A0, A1, A2, A3);
  }

all_done: ;
}

extern "C" void kernel_launch(void* const* d_in, const int* in_sizes, int n_in,
                              void* d_out, int out_size, void* d_ws, size_t ws_size,
                              hipStream_t stream) {
  const float* root = (const float*)d_in[0];
  const float* lg   = (const float*)d_in[1];
  const int*   pidx = (const int*)d_in[2];
  float* out        = (float*)d_out;

  // (kLayers+1)*kM floats = 262144 float4 -> sentinel every launch
  // (harness poisons d_out once but never between graph replays; stale
  // positive values from the previous replay would be read as ready).
  init_sentinel_kernel<<<1024, 256, 0, stream>>>((float4*)out);

  bayes_chain_kernel<<<kBlocks, kThreads, 0, stream>>>(root, lg, pidx, out);
}

// Round 17
// 102.267 us; speedup vs baseline: 1.8450x; 1.8450x over previous
//
#include <hip/hip_runtime.h>
#include <stdint.h>

// Layered Bayesian net marginal chain: 63 sequential layers, M=16384 nodes,
// K=4 parents, C=16 CPT entries per node.
//
// Structure (R5->R12, best=93us, PASSED): global fine-grained dataflow.
// Marginals are strictly positive, so the DATA is its own ready-flag:
// sentinel-init rows, relaxed AGENT-scope write-through stores, consumers
// poll their own 4 parent slots (inline-asm sc0 sc1 loads, hand-placed
// counted vmcnt, staggered batches, per-lane early publish). Statics are
// compiler-owned loads prefetched 2 links deep; the R12 body keeps a newer
// compiler refill in flight at every consumption point, so the compiler's
// register-tracked waits stay COUNTED (cheap), never vmcnt(0).
//
// R13 post-mortem (189us, reverted): skew-1 state machine put the statics
// consumption at a point with no newer compiler loads in flight -> the
// compiler emitted vmcnt(0) there, draining both poll batches every link
// (R10's bug back), plus stale-flagged batches and heavier checks.
//
// R14 = R12 + two surgical tweaks inside the proven body:
//  1. first poll batch issued BEFORE SIG16 (addresses need only IDX, in
//     regs): its RTT overlaps the sigmoid burst, trimming exit-serial.
//  2. THREE staggered batches (P/Q/R) with vmcnt(8) per check: detection
//     cadence RTT/2 -> RTT/3. Invariant: vmcnt(8) retires exactly the
//     checked batch + everything older (publish stores swept), leaving the
//     two newest batches (8 loads) in flight.

namespace {
constexpr int kLayers  = 63;      // links (row t -> row t+1), rows 0..63
constexpr int kM       = 16384;   // nodes per layer
constexpr int kBlocks  = 256;     // 1 block (1 wave) per CU
constexpr int kThreads = 64;      // kBlocks*kThreads == kM, 1 thread per node
constexpr float kSentinel = -1.0f;
}

// Re-init the whole out buffer (rows 0..63) to sentinel each launch.
// Normal cached stores; kernel-end writeback makes them visible to the
// chain kernel's agent-scope (cache-bypassing) polls.
__global__ void init_sentinel_kernel(float4* __restrict__ out4) {
  int i = blockIdx.x * blockDim.x + threadIdx.x;   // 262144 float4 total
  out4[i] = make_float4(kSentinel, kSentinel, kSentinel, kSentinel);
}

__device__ __forceinline__ float fsig(float x) {
  // sigmoid; fp32 fast-math is far inside the 1.8e-2 abs threshold
  return __fdividef(1.0f, 1.0f + __expf(-x));
}

// Agent-scope (device-coherent) accesses: bypass the non-coherent per-XCD
// L1/L2, hit the coherence point directly. No cache-wide maintenance.
__device__ __forceinline__ void agent_store(float* p, float v) {
  __hip_atomic_store(p, v, __ATOMIC_RELAXED, __HIP_MEMORY_SCOPE_AGENT);
}
__device__ __forceinline__ float agent_load(const float* p) {
  return __hip_atomic_load(p, __ATOMIC_RELAXED, __HIP_MEMORY_SCOPE_AGENT);
}

// Issue 4 agent read-through polls as raw asm: WE own the waitcnt (the
// compiler cannot see these), giving exact control of check cadence.
#define POLL_ISSUE4(r0, r1, r2, r3, A0, A1, A2, A3)                         \
  asm volatile("global_load_dword %0, %4, off sc0 sc1\n\t"                  \
               "global_load_dword %1, %5, off sc0 sc1\n\t"                  \
               "global_load_dword %2, %6, off sc0 sc1\n\t"                  \
               "global_load_dword %3, %7, off sc0 sc1"                      \
               : "=&v"(r0), "=&v"(r1), "=&v"(r2), "=&v"(r3)                 \
               : "v"(A0), "v"(A1), "v"(A2), "v"(A3)                         \
               : "memory")

// weight[c] factorizes over parents (MSB-first bit order, matches _configs):
// c = b0 b1 b2 b3, fk(1)=pk, fk(0)=1-pk.
__device__ __forceinline__ float combine16(const float* s,
                                           float p0, float p1, float p2, float p3) {
  float q0 = 1.0f - p0, q1 = 1.0f - p1, q2 = 1.0f - p2, q3 = 1.0f - p3;
  float w0 = q2 * q3, w1 = q2 * p3, w2 = p2 * q3, w3 = p2 * p3;   // (b2,b3)
  float i0 = s[0]  * w0 + s[1]  * w1 + s[2]  * w2 + s[3]  * w3;   // (b0,b1)=(0,0)
  float i1 = s[4]  * w0 + s[5]  * w1 + s[6]  * w2 + s[7]  * w3;   // (0,1)
  float i2 = s[8]  * w0 + s[9]  * w1 + s[10] * w2 + s[11] * w3;   // (1,0)
  float i3 = s[12] * w0 + s[13] * w1 + s[14] * w2 + s[15] * w3;   // (1,1)
  return (q0 * q1) * i0 + (q0 * p1) * i1 + (p0 * q1) * i2 + (p0 * p1) * i3;
}

#define SIG16(S, V0, V1, V2, V3)                                              \
  S[0]  = fsig((V0).x); S[1]  = fsig((V0).y); S[2]  = fsig((V0).z); S[3]  = fsig((V0).w); \
  S[4]  = fsig((V1).x); S[5]  = fsig((V1).y); S[6]  = fsig((V1).z); S[7]  = fsig((V1).w); \
  S[8]  = fsig((V2).x); S[9]  = fsig((V2).y); S[10] = fsig((V2).z); S[11] = fsig((V2).w); \
  S[12] = fsig((V3).x); S[13] = fsig((V3).y); S[14] = fsig((V3).z); S[15] = fsig((V3).w)

// One layer body (R12 structure). Consumes statics for layer t (loaded two
// bodies ago, HW-retired by the intervening spin's counted waits); post-spin
// refills the SAME buffer with layer t+2's statics via compiler loads (in
// flight across the next spin -> keeps the next consumption wait COUNTED).
#define CHAIN_BODY(IDX, L0, L1, L2, L3)                                      \
  {                                                                          \
    const float* A0 = &prev[(IDX).x];                                        \
    const float* A1 = &prev[(IDX).y];                                        \
    const float* A2 = &prev[(IDX).z];                                        \
    const float* A3 = &prev[(IDX).w];                                        \
    float* const dst = &cur[m];                                              \
    /* batch P issued ASAP: its RTT overlaps the sigmoid burst below */      \
    float pP0, pP1, pP2, pP3, pQ0, pQ1, pQ2, pQ3, pR0, pR1, pR2, pR3;        \
    POLL_ISSUE4(pP0, pP1, pP2, pP3, A0, A1, A2, A3);                         \
    /* statics sigmoids: L-regs retired 2 bodies ago; the other buffer's */  \
    /* refill is newest-in-flight -> compiler wait stays counted/cheap  */   \
    float s[16]; SIG16(s, L0, L1, L2, L3);                                   \
    __builtin_amdgcn_s_sleep(5);       /* ~RTT/3 stagger */                  \
    POLL_ISSUE4(pQ0, pQ1, pQ2, pQ3, A0, A1, A2, A3);                         \
    __builtin_amdgcn_s_sleep(5);                                             \
    POLL_ISSUE4(pR0, pR1, pR2, pR3, A0, A1, A2, A3);                         \
    __builtin_amdgcn_sched_barrier(0);                                       \
    bool done = false;                                                       \
    int tries = 0;                                                           \
    for (;;) {                                                               \
      /* vmcnt(8): retires checked batch + all older (stores swept),   */   \
      /* leaves the two newest batches (8 loads) in flight.            */   \
      asm volatile("s_waitcnt vmcnt(8)" ::: "memory");                       \
      __builtin_amdgcn_sched_barrier(0);                                     \
      {                                                                      \
        bool newly = !done & (pP0 >= 0.f) & (pP1 >= 0.f) & (pP2 >= 0.f) & (pP3 >= 0.f); \
        if (newly) {  /* divergent: newly-ready lanes publish NOW */         \
          done = true;                                                       \
          agent_store(dst, combine16(s, pP0, pP1, pP2, pP3));                \
        }                                                                    \
      }                                                                      \
      if (__all(done)) break;                                                \
      POLL_ISSUE4(pP0, pP1, pP2, pP3, A0, A1, A2, A3);                       \
      asm volatile("s_waitcnt vmcnt(8)" ::: "memory");                       \
      __builtin_amdgcn_sched_barrier(0);                                     \
      {                                                                      \
        bool newly = !done & (pQ0 >= 0.f) & (pQ1 >= 0.f) & (pQ2 >= 0.f) & (pQ3 >= 0.f); \
        if (newly) {                                                         \
          done = true;                                                       \
          agent_store(dst, combine16(s, pQ0, pQ1, pQ2, pQ3));                \
        }                                                                    \
      }                                                                      \
      if (__all(done)) break;                                                \
      POLL_ISSUE4(pQ0, pQ1, pQ2, pQ3, A0, A1, A2, A3);                       \
      asm volatile("s_waitcnt vmcnt(8)" ::: "memory");                       \
      __builtin_amdgcn_sched_barrier(0);                                     \
      {                                                                      \
        bool newly = !done & (pR0 >= 0.f) & (pR1 >= 0.f) & (pR2 >= 0.f) & (pR3 >= 0.f); \
        if (newly) {                                                         \
          done = true;                                                       \
          agent_store(dst, combine16(s, pR0, pR1, pR2, pR3));                \
        }                                                                    \
      }                                                                      \
      if (__all(done)) break;                                                \
      if (++tries > 2048) {                                                  \
        /* escalation valve: drain manual queue, proven compiler loads */    \
        asm volatile("s_waitcnt vmcnt(0)" ::: "memory");                     \
        __builtin_amdgcn_sched_barrier(0);                                   \
        while (!__all(done)) {                                               \
          float x0 = agent_load(A0), x1 = agent_load(A1);                    \
          float x2 = agent_load(A2), x3 = agent_load(A3);                    \
          bool newly = !done & (x0 >= 0.f) & (x1 >= 0.f) & (x2 >= 0.f) & (x3 >= 0.f); \
          if (newly) {                                                       \
            done = true;                                                     \
            agent_store(dst, combine16(s, x0, x1, x2, x3));                  \
          }                                                                  \
        }                                                                    \
        break;                                                               \
      }                                                                      \
      POLL_ISSUE4(pR0, pR1, pR2, pR3, A0, A1, A2, A3);                       \
    }                                                                        \
    __builtin_amdgcn_sched_barrier(0);                                       \
    /* post-spin: refill this buffer with layer t+2's statics (compiler  */ \
    /* loads, in flight across the next spin -> next wait stays counted) */ \
    {                                                                        \
      const int tpp = (t + 2 <= kLayers - 1) ? (t + 2) : (kLayers - 1);      \
      const size_t bn = (size_t)tpp * kM + m;                                \
      (IDX) = pidx[bn];                                                      \
      (L0) = lg[bn * 4 + 0]; (L1) = lg[bn * 4 + 1];                          \
      (L2) = lg[bn * 4 + 2]; (L3) = lg[bn * 4 + 3];                          \
    }                                                                        \
    prev = cur;                                                              \
    cur += kM;                                                               \
  }

__global__ __launch_bounds__(kThreads, 1) void bayes_chain_kernel(
    const float* __restrict__ root_logits,   // [kM]
    const float* __restrict__ layer_logits,  // [kLayers][kM][16]
    const int*   __restrict__ parent_idx,    // [kLayers][kM][4]
    float* __restrict__ out)                 // [kLayers+1][kM]
{
  const int m = blockIdx.x * kThreads + threadIdx.x;

  const int4*   pidx = reinterpret_cast<const int4*>(parent_idx);     // [63][M]
  const float4* lg   = reinterpret_cast<const float4*>(layer_logits); // [63][M][4]

  // ---- row 0: root marginals, write-through so consumers' polls see them ----
  agent_store(&out[m], fsig(root_logits[m]));

  // 2-deep statics pipeline: buffer A = layer 0, buffer B = layer 1
  // (compiler loads; no asm polls outstanding yet, waits here are clean).
  int4   idxA = pidx[m];
  float4 la0 = lg[(size_t)m * 4 + 0], la1 = lg[(size_t)m * 4 + 1];
  float4 la2 = lg[(size_t)m * 4 + 2], la3 = lg[(size_t)m * 4 + 3];
  const size_t b1 = (size_t)kM + m;
  int4   idxB = pidx[b1];
  float4 lb0 = lg[b1 * 4 + 0], lb1 = lg[b1 * 4 + 1];
  float4 lb2 = lg[b1 * 4 + 2], lb3 = lg[b1 * 4 + 3];

  const float* prev = out;
  float*       cur  = out + kM;

  int t = 0;
  for (;;) {
    CHAIN_BODY(idxA, la0, la1, la2, la3);   // even layers consume/refill A
    if (++t == kLayers) break;
    CHAIN_BODY(idxB, lb0, lb1, lb2, lb3);   // odd layers consume/refill B
    if (++t == kLayers) break;
  }
}

extern "C" void kernel_launch(void* const* d_in, const int* in_sizes, int n_in,
                              void* d_out, int out_size, void* d_ws, size_t ws_size,
                              hipStream_t stream) {
  const float* root = (const float*)d_in[0];
  const float* lg   = (const float*)d_in[1];
  const int*   pidx = (const int*)d_in[2];
  float* out        = (float*)d_out;

  // (kLayers+1)*kM floats = 262144 float4 -> sentinel every launch
  // (harness poisons d_out once but never between graph replays; stale
  // positive values from the previous replay would be read as ready).
  init_sentinel_kernel<<<1024, 256, 0, stream>>>((float4*)out);

  bayes_chain_kernel<<<kBlocks, kThreads, 0, stream>>>(root, lg, pidx, out);
}

// Round 18
// 92.853 us; speedup vs baseline: 2.0321x; 1.1014x over previous
//
#include <hip/hip_runtime.h>
#include <stdint.h>

// Layered Bayesian net marginal chain: 63 sequential layers, M=16384 nodes,
// K=4 parents, C=16 CPT entries per node.
//
// FINAL (R12 revert, best=93us, PASSED): global fine-grained dataflow.
// Marginals are strictly positive, so the DATA is its own ready-flag:
// sentinel-init rows, relaxed AGENT-scope write-through stores, consumers
// poll their own 4 parent slots (inline-asm sc0 sc1 loads, hand-placed
// vmcnt(4), staggered A/B batches, per-lane early publish). Statics are
// compiler-owned loads prefetched 2 links deep (hardware-retired by the
// spin's vmcnt(4), so compiler waits stay counted/cheap). No barriers,
// no fences.
//
// Why this is the roofline (measured, 63 sequential links):
//  - counter barriers:        3.9 us/link  (R3)
//  - pair fusion:            11.2 us/barrier (R4: uncoalesced scatter)
//  - XCD-replicated sync:      29 us/link  (R6: 8x input streaming)
//  - skew-1 state machine:    3.0 us/link  (R13: compiler vmcnt(0) drain)
//  - poll-traffic reduction:   null        (R7)
//  - queue-order fast path:    null        (R8)
//  - 3-batch RTT/3 cadence:   regressed    (R14: +50% poll traffic)
//  -> remaining 1.45 us/link = producer-store->L3 visibility + max-plus
//     coupling of device-scope dataflow; not contention/order/cadence.

namespace {
constexpr int kLayers  = 63;      // hidden layers
constexpr int kM       = 16384;   // nodes per layer
constexpr int kBlocks  = 256;     // 1 block (1 wave) per CU
constexpr int kThreads = 64;      // kBlocks*kThreads == kM, 1 thread per node
constexpr float kSentinel = -1.0f;
}

// Re-init the whole out buffer (rows 0..63) to sentinel each launch.
// Normal cached stores; kernel-end writeback makes them visible to the
// chain kernel's agent-scope (cache-bypassing) polls.
__global__ void init_sentinel_kernel(float4* __restrict__ out4) {
  int i = blockIdx.x * blockDim.x + threadIdx.x;   // 262144 float4 total
  out4[i] = make_float4(kSentinel, kSentinel, kSentinel, kSentinel);
}

__device__ __forceinline__ float fsig(float x) {
  // sigmoid; fp32 fast-math is far inside the 1.8e-2 abs threshold
  return __fdividef(1.0f, 1.0f + __expf(-x));
}

// Agent-scope (device-coherent) accesses: bypass the non-coherent per-XCD
// L1/L2, hit the coherence point directly. No cache-wide maintenance.
__device__ __forceinline__ void agent_store(float* p, float v) {
  __hip_atomic_store(p, v, __ATOMIC_RELAXED, __HIP_MEMORY_SCOPE_AGENT);
}
__device__ __forceinline__ float agent_load(const float* p) {
  return __hip_atomic_load(p, __ATOMIC_RELAXED, __HIP_MEMORY_SCOPE_AGENT);
}

// Issue 4 agent read-through polls as raw asm: WE own the waitcnt (the
// compiler cannot see these), giving exact control of check cadence.
#define POLL_ISSUE4(r0, r1, r2, r3, A0, A1, A2, A3)                         \
  asm volatile("global_load_dword %0, %4, off sc0 sc1\n\t"                  \
               "global_load_dword %1, %5, off sc0 sc1\n\t"                  \
               "global_load_dword %2, %6, off sc0 sc1\n\t"                  \
               "global_load_dword %3, %7, off sc0 sc1"                      \
               : "=&v"(r0), "=&v"(r1), "=&v"(r2), "=&v"(r3)                 \
               : "v"(A0), "v"(A1), "v"(A2), "v"(A3)                         \
               : "memory")

// weight[c] factorizes over parents (MSB-first bit order, matches _configs):
// c = b0 b1 b2 b3, fk(1)=pk, fk(0)=1-pk.
__device__ __forceinline__ float combine16(const float* s,
                                           float p0, float p1, float p2, float p3) {
  float q0 = 1.0f - p0, q1 = 1.0f - p1, q2 = 1.0f - p2, q3 = 1.0f - p3;
  float w0 = q2 * q3, w1 = q2 * p3, w2 = p2 * q3, w3 = p2 * p3;   // (b2,b3)
  float i0 = s[0]  * w0 + s[1]  * w1 + s[2]  * w2 + s[3]  * w3;   // (b0,b1)=(0,0)
  float i1 = s[4]  * w0 + s[5]  * w1 + s[6]  * w2 + s[7]  * w3;   // (0,1)
  float i2 = s[8]  * w0 + s[9]  * w1 + s[10] * w2 + s[11] * w3;   // (1,0)
  float i3 = s[12] * w0 + s[13] * w1 + s[14] * w2 + s[15] * w3;   // (1,1)
  return (q0 * q1) * i0 + (q0 * p1) * i1 + (p0 * q1) * i2 + (p0 * p1) * i3;
}

#define SIG16(S, V0, V1, V2, V3)                                              \
  S[0]  = fsig((V0).x); S[1]  = fsig((V0).y); S[2]  = fsig((V0).z); S[3]  = fsig((V0).w); \
  S[4]  = fsig((V1).x); S[5]  = fsig((V1).y); S[6]  = fsig((V1).z); S[7]  = fsig((V1).w); \
  S[8]  = fsig((V2).x); S[9]  = fsig((V2).y); S[10] = fsig((V2).z); S[11] = fsig((V2).w); \
  S[12] = fsig((V3).x); S[13] = fsig((V3).y); S[14] = fsig((V3).z); S[15] = fsig((V3).w)

// One layer body. Consumes statics (IDX, L0..L3) for layer t (loaded two
// bodies ago, HW-retired by the intervening spin's vmcnt(4)); spin is the
// exact R10-passing code; post-spin refills the SAME buffer with layer
// t+2's statics via ordinary compiler loads.
#define CHAIN_BODY(IDX, L0, L1, L2, L3)                                      \
  {                                                                          \
    /* pre-spin: compiler's counted wait here only drains ~4 leftover    */ \
    /* polls (~200ns); the statics themselves retired during last spin.  */ \
    float s[16]; SIG16(s, L0, L1, L2, L3);                                   \
    const float* A0 = &prev[(IDX).x];                                        \
    const float* A1 = &prev[(IDX).y];                                        \
    const float* A2 = &prev[(IDX).z];                                        \
    const float* A3 = &prev[(IDX).w];                                        \
    float* const dst = &cur[m];                                              \
    __builtin_amdgcn_sched_barrier(0);                                       \
    /* ---- staggered spin, per-lane early publish (R10, unchanged) ---- */ \
    float pA0, pA1, pA2, pA3, pB0, pB1, pB2, pB3;                            \
    POLL_ISSUE4(pA0, pA1, pA2, pA3, A0, A1, A2, A3);                         \
    __builtin_amdgcn_s_sleep(8);       /* ~213ns: offset batches ~RTT/2 */   \
    POLL_ISSUE4(pB0, pB1, pB2, pB3, A0, A1, A2, A3);                         \
    bool done = false;                                                       \
    int tries = 0;                                                           \
    for (;;) {                                                               \
      /* vmcnt(4): leaves exactly the newest 4 outstanding; retires the */  \
      /* checked batch AND everything older (leftovers, statics, store) */  \
      asm volatile("s_waitcnt vmcnt(4)" ::: "memory");                       \
      __builtin_amdgcn_sched_barrier(0);                                     \
      {                                                                      \
        bool newly = !done & (pA0 >= 0.f) & (pA1 >= 0.f) & (pA2 >= 0.f) & (pA3 >= 0.f); \
        if (newly) {  /* divergent: newly-ready lanes publish NOW */         \
          done = true;                                                       \
          agent_store(dst, combine16(s, pA0, pA1, pA2, pA3));                \
        }                                                                    \
      }                                                                      \
      if (__all(done)) break;                                                \
      POLL_ISSUE4(pA0, pA1, pA2, pA3, A0, A1, A2, A3);                       \
      asm volatile("s_waitcnt vmcnt(4)" ::: "memory");                       \
      __builtin_amdgcn_sched_barrier(0);                                     \
      {                                                                      \
        bool newly = !done & (pB0 >= 0.f) & (pB1 >= 0.f) & (pB2 >= 0.f) & (pB3 >= 0.f); \
        if (newly) {                                                         \
          done = true;                                                       \
          agent_store(dst, combine16(s, pB0, pB1, pB2, pB3));                \
        }                                                                    \
      }                                                                      \
      if (__all(done)) break;                                                \
      if (++tries > 512) {                                                   \
        /* escalation valve: drain manual queue, proven compiler loads */    \
        asm volatile("s_waitcnt vmcnt(0)" ::: "memory");                     \
        __builtin_amdgcn_sched_barrier(0);                                   \
        while (!__all(done)) {                                               \
          float x0 = agent_load(A0), x1 = agent_load(A1);                    \
          float x2 = agent_load(A2), x3 = agent_load(A3);                    \
          bool newly = !done & (x0 >= 0.f) & (x1 >= 0.f) & (x2 >= 0.f) & (x3 >= 0.f); \
          if (newly) {                                                       \
            done = true;                                                     \
            agent_store(dst, combine16(s, x0, x1, x2, x3));                  \
          }                                                                  \
        }                                                                    \
        break;                                                               \
      }                                                                      \
      POLL_ISSUE4(pB0, pB1, pB2, pB3, A0, A1, A2, A3);                       \
    }                                                                        \
    __builtin_amdgcn_sched_barrier(0);                                       \
    /* ---- post-spin: refill this buffer with layer t+2's statics via  */  \
    /* ordinary compiler loads (in flight across the next spin, which   */  \
    /* hardware-retires them; compiler owns the consumption wait).      */  \
    {                                                                        \
      const int tpp = (t + 2 <= kLayers - 1) ? (t + 2) : (kLayers - 1);      \
      const size_t bn = (size_t)tpp * kM + m;                                \
      (IDX) = pidx[bn];                                                      \
      (L0) = lg[bn * 4 + 0]; (L1) = lg[bn * 4 + 1];                          \
      (L2) = lg[bn * 4 + 2]; (L3) = lg[bn * 4 + 3];                          \
    }                                                                        \
    prev = cur;                                                              \
    cur += kM;                                                               \
  }

__global__ __launch_bounds__(kThreads, 1) void bayes_chain_kernel(
    const float* __restrict__ root_logits,   // [kM]
    const float* __restrict__ layer_logits,  // [kLayers][kM][16]
    const int*   __restrict__ parent_idx,    // [kLayers][kM][4]
    float* __restrict__ out)                 // [kLayers+1][kM]
{
  const int m = blockIdx.x * kThreads + threadIdx.x;

  const int4*   pidx = reinterpret_cast<const int4*>(parent_idx);     // [63][M]
  const float4* lg   = reinterpret_cast<const float4*>(layer_logits); // [63][M][4]

  // ---- row 0: root marginals, write-through so consumers' polls see them ----
  agent_store(&out[m], fsig(root_logits[m]));

  // 2-deep statics pipeline: buffer A = layer 0, buffer B = layer 1
  // (compiler loads; no asm polls outstanding yet, waits here are clean).
  int4   idxA = pidx[m];
  float4 la0 = lg[(size_t)m * 4 + 0], la1 = lg[(size_t)m * 4 + 1];
  float4 la2 = lg[(size_t)m * 4 + 2], la3 = lg[(size_t)m * 4 + 3];
  const size_t b1 = (size_t)kM + m;
  int4   idxB = pidx[b1];
  float4 lb0 = lg[b1 * 4 + 0], lb1 = lg[b1 * 4 + 1];
  float4 lb2 = lg[b1 * 4 + 2], lb3 = lg[b1 * 4 + 3];

  const float* prev = out;
  float*       cur  = out + kM;

  int t = 0;
  for (;;) {
    CHAIN_BODY(idxA, la0, la1, la2, la3);   // even layers consume/refill A
    if (++t == kLayers) break;
    CHAIN_BODY(idxB, lb0, lb1, lb2, lb3);   // odd layers consume/refill B
    if (++t == kLayers) break;
  }
}

extern "C" void kernel_launch(void* const* d_in, const int* in_sizes, int n_in,
                              void* d_out, int out_size, void* d_ws, size_t ws_size,
                              hipStream_t stream) {
  const float* root = (const float*)d_in[0];
  const float* lg   = (const float*)d_in[1];
  const int*   pidx = (const int*)d_in[2];
  float* out        = (float*)d_out;

  // (kLayers+1)*kM floats = 262144 float4 -> sentinel every launch
  // (harness poisons d_out once but never between graph replays; stale
  // positive values from the previous replay would be read as ready).
  init_sentinel_kernel<<<1024, 256, 0, stream>>>((float4*)out);

  bayes_chain_kernel<<<kBlocks, kThreads, 0, stream>>>(root, lg, pidx, out);
}